// Round 2
// baseline (259.055 us; speedup 1.0000x reference)
//
#include <hip/hip_runtime.h>

#define SEQ    2048
#define BATCH  2
#define DMODEL 1024
#define NHEAD  16
#define DH     64
#define MROWS  (SEQ*BATCH)        // 4096
#define RS     (BATCH*DMODEL)     // 2048
#define LN_EPS 1e-12f
#define LOG2E  1.4426950408889634f

typedef __attribute__((ext_vector_type(8))) short short8;
typedef __attribute__((ext_vector_type(4))) float floatx4;

#define AS_GLOBAL __attribute__((address_space(1)))
#define AS_LDS    __attribute__((address_space(3)))

// ---- bf16 bit helpers (intermediates only; in/out are fp32) ----
__device__ __forceinline__ float bf2f(unsigned short s) {
    union { unsigned u; float f; } a; a.u = ((unsigned)s) << 16; return a.f;
}
__device__ __forceinline__ unsigned short f2bf(float x) {
    union { float f; unsigned u; } a; a.f = x;
    unsigned r = a.u + 0x7fffu + ((a.u >> 16) & 1u);
    return (unsigned short)(r >> 16);
}
// HW packed conversion: lo = cvt(a), hi = cvt(b). One instr for two bf16.
__device__ __forceinline__ unsigned cvt_pk_bf16(float a, float b) {
    unsigned r;
    asm("v_cvt_pk_bf16_f32 %0, %1, %2" : "=v"(r) : "v"(a), "v"(b));
    return r;
}
// 3-input max, single VALU op (VOP3).
__device__ __forceinline__ float max3f(float a, float b, float c) {
    float r;
    asm("v_max3_f32 %0, %1, %2, %3" : "=v"(r) : "v"(a), "v"(b), "v"(c));
    return r;
}
__device__ __forceinline__ float fast_exp2(float x) {
#if __has_builtin(__builtin_amdgcn_exp2f)
    return __builtin_amdgcn_exp2f(x);
#else
    return exp2f(x);
#endif
}
__device__ __forceinline__ uint4 cvt8(const float* __restrict__ p) {
    float4 x0 = *(const float4*)(p);
    float4 x1 = *(const float4*)(p + 4);
    union { uint4 u; unsigned short s[8]; } r;
    r.s[0] = f2bf(x0.x); r.s[1] = f2bf(x0.y);
    r.s[2] = f2bf(x0.z); r.s[3] = f2bf(x0.w);
    r.s[4] = f2bf(x1.x); r.s[5] = f2bf(x1.y);
    r.s[6] = f2bf(x1.z); r.s[7] = f2bf(x1.w);
    return r.u;
}
__device__ __forceinline__ uint4 cvt8s(const float* __restrict__ p, float sc) {
    float4 x0 = *(const float4*)(p);
    float4 x1 = *(const float4*)(p + 4);
    union { uint4 u; unsigned short s[8]; } r;
    r.s[0] = f2bf(x0.x*sc); r.s[1] = f2bf(x0.y*sc);
    r.s[2] = f2bf(x0.z*sc); r.s[3] = f2bf(x0.w*sc);
    r.s[4] = f2bf(x1.x*sc); r.s[5] = f2bf(x1.y*sc);
    r.s[6] = f2bf(x1.z*sc); r.s[7] = f2bf(x1.w*sc);
    return r.u;
}

__global__ void beacon_kernel(float* out, float val) {
    if (threadIdx.x == 0) out[0] = val;
}

// ---------------------------------------------------------------
// One-shot fp32 -> bf16 conversion of inputs + weights.
// Wq (z==3) is pre-scaled by log2(e) so attention softmax can use
// native exp2 without a per-score multiply.
// ---------------------------------------------------------------
__global__ __launch_bounds__(256)
void cvt_kernel(const float* __restrict__ s0, const float* __restrict__ s1,
                const float* __restrict__ s2, const float* __restrict__ s3,
                const float* __restrict__ s4, const float* __restrict__ s5,
                const float* __restrict__ s6,
                unsigned short* __restrict__ d0, unsigned short* __restrict__ d1,
                unsigned short* __restrict__ d2, unsigned short* __restrict__ d3,
                unsigned short* __restrict__ d4, unsigned short* __restrict__ d5,
                unsigned short* __restrict__ d6)
{
    const float* srcs[7] = {s0, s1, s2, s3, s4, s5, s6};
    unsigned short* dsts[7] = {d0, d1, d2, d3, d4, d5, d6};
    const int cnts[7] = {4194304, 4194304, 4194304, 1048576, 1048576, 1048576, 1048576};
    const float scl[7] = {1.f, 1.f, 1.f, LOG2E, 1.f, 1.f, 1.f};
    const int z = blockIdx.z;
    const float* src = srcs[z];
    unsigned short* dst = dsts[z];
    const int count = cnts[z];
    const float sc = scl[z];
    const int stride = gridDim.x * 256 * 8;
    for (int i = (blockIdx.x * 256 + threadIdx.x) * 8; i < count; i += stride)
        *(uint4*)&dst[i] = cvt8s(&src[i], sc);
}

// ---------------------------------------------------------------
// V transpose: Vb [token=(s*2+b)][dmodel] -> VT [bh=32][d=64][s=2048]
// ---------------------------------------------------------------
__global__ __launch_bounds__(256)
void vt_kernel(const unsigned short* __restrict__ Vb,
               unsigned short* __restrict__ VT)
{
    __shared__ __align__(16) short T[64*72];
    const int tid = threadIdx.x;
    const int s0 = blockIdx.x * 64;
    const int bh = blockIdx.y;
    const int b = bh >> 4, h = bh & 15;

    #pragma unroll
    for (int rep = 0; rep < 2; ++rep) {
        int c = tid + rep * 256;
        int s = c >> 3, cc = c & 7;
        *(uint4*)&T[s*72 + cc*8] =
            *(const uint4*)&Vb[((s0 + s) * BATCH + b) * DMODEL + h*64 + cc*8];
    }
    __syncthreads();
    #pragma unroll
    for (int rep = 0; rep < 2; ++rep) {
        int o = tid + rep * 256;
        int d = o >> 3, sc = o & 7;
        union { uint4 u; unsigned short e[8]; } pk;
        #pragma unroll
        for (int j = 0; j < 8; ++j)
            pk.e[j] = (unsigned short)T[(sc*8 + j)*72 + d];
        *(uint4*)&VT[bh*(DH*SEQ) + d*SEQ + s0 + sc*8] = pk.u;
    }
}

// ---------------------------------------------------------------
// bf16 MFMA GEMM, double-buffered async global->LDS staging:
// prefetch K-step t+1 issued before compute of t; single barrier
// per step drains the prefetch AFTER compute (T3 minimum recipe).
// ---------------------------------------------------------------
template<int OUTF32>
__device__ __forceinline__ void gemm_bf16_body(
    const unsigned short* __restrict__ A,
    const unsigned short* __restrict__ W,
    const float* __restrict__ bias, float bscale,
    void* __restrict__ Cout)
{
    __shared__ __align__(16) short Alds[2][128*32];
    __shared__ __align__(16) short Blds[2][128*32];

    const int tid  = threadIdx.x;
    const int lane = tid & 63;
    const int wave = tid >> 6;
    const int lrow = lane & 15;
    const int lq   = lane >> 4;
    const int m0 = blockIdx.x * 128;
    const int n0 = blockIdx.y * 128;
    const int mw = (wave >> 1) * 64;
    const int nw = (wave & 1) * 64;
    const int K  = DMODEL;

    const int chunk0 = tid;
    const int chunk1 = tid + 256;
    const int row0 = chunk0 >> 2, col0 = (chunk0 & 3) << 3;
    const int row1 = chunk1 >> 2, col1 = (chunk1 & 3) << 3;
    const unsigned short* gA0 = &A[(m0 + row0) * K + col0];
    const unsigned short* gA1 = &A[(m0 + row1) * K + col1];
    const unsigned short* gB0 = &W[(n0 + row0) * K + col0];
    const unsigned short* gB1 = &W[(n0 + row1) * K + col1];

    auto stage = [&](int k0, int b) {
        __builtin_amdgcn_global_load_lds((const AS_GLOBAL unsigned int*)(gA0 + k0),
            (AS_LDS unsigned int*)&Alds[b][(wave*64)*8], 16, 0, 0);
        __builtin_amdgcn_global_load_lds((const AS_GLOBAL unsigned int*)(gA1 + k0),
            (AS_LDS unsigned int*)&Alds[b][(256 + wave*64)*8], 16, 0, 0);
        __builtin_amdgcn_global_load_lds((const AS_GLOBAL unsigned int*)(gB0 + k0),
            (AS_LDS unsigned int*)&Blds[b][(wave*64)*8], 16, 0, 0);
        __builtin_amdgcn_global_load_lds((const AS_GLOBAL unsigned int*)(gB1 + k0),
            (AS_LDS unsigned int*)&Blds[b][(256 + wave*64)*8], 16, 0, 0);
    };

    floatx4 zero = {0.f, 0.f, 0.f, 0.f};
    floatx4 acc[4][4];
    #pragma unroll
    for (int i = 0; i < 4; ++i)
        #pragma unroll
        for (int j = 0; j < 4; ++j) acc[i][j] = zero;

    stage(0, 0);
    __syncthreads();

    for (int k0 = 0; k0 < K; k0 += 32) {
        const int cur = (k0 >> 5) & 1;
        if (k0 + 32 < K) stage(k0 + 32, cur ^ 1);   // prefetch in flight
        short8 af[4], bfg[4];
        #pragma unroll
        for (int mi = 0; mi < 4; ++mi)
            af[mi] = *(const short8*)&Alds[cur][(mw + mi*16 + lrow)*32 + lq*8];
        #pragma unroll
        for (int ni = 0; ni < 4; ++ni)
            bfg[ni] = *(const short8*)&Blds[cur][(nw + ni*16 + lrow)*32 + lq*8];
        #pragma unroll
        for (int mi = 0; mi < 4; ++mi)
            #pragma unroll
            for (int ni = 0; ni < 4; ++ni)
                acc[mi][ni] = __builtin_amdgcn_mfma_f32_16x16x32_bf16(af[mi], bfg[ni], acc[mi][ni], 0, 0, 0);
        __syncthreads();   // drains prefetch; protects buf reuse
    }

    #pragma unroll
    for (int mi = 0; mi < 4; ++mi) {
        #pragma unroll
        for (int ni = 0; ni < 4; ++ni) {
            int n = n0 + nw + ni*16 + lrow;
            float bv_ = bias[n] * bscale;
            #pragma unroll
            for (int r = 0; r < 4; ++r) {
                int m = m0 + mw + mi*16 + lq*4 + r;
                float v = acc[mi][ni][r] + bv_;
                if (OUTF32) ((float*)Cout)[m * DMODEL + n] = v;
                else ((unsigned short*)Cout)[m * DMODEL + n] = f2bf(v);
            }
        }
    }
}

__global__ __launch_bounds__(256)
void qkv_bf16(const unsigned short* __restrict__ qb, const unsigned short* __restrict__ kb,
              const unsigned short* __restrict__ vb,
              const unsigned short* __restrict__ Wqb, const float* __restrict__ bq,
              const unsigned short* __restrict__ Wkb, const float* __restrict__ bk,
              const unsigned short* __restrict__ Wvb, const float* __restrict__ bv,
              unsigned short* __restrict__ Qo, unsigned short* __restrict__ Ko,
              unsigned short* __restrict__ Vo)
{
    const unsigned short *A, *W; const float* B; unsigned short* C; float bs;
    if (blockIdx.z == 0)      { A = qb; W = Wqb; B = bq; C = Qo; bs = LOG2E; }
    else if (blockIdx.z == 1) { A = kb; W = Wkb; B = bk; C = Ko; bs = 1.f; }
    else                      { A = vb; W = Wvb; B = bv; C = Vo; bs = 1.f; }
    gemm_bf16_body<0>(A, W, B, bs, C);
}

__global__ __launch_bounds__(256)
void oproj_bf16(const unsigned short* __restrict__ Cx,
                const unsigned short* __restrict__ Wob, const float* __restrict__ bo,
                float* __restrict__ O32)
{
    gemm_bf16_body<1>(Cx, Wob, bo, 1.f, O32);
}

// ---------------- fallback (fused-cvt) GEMMs ----------------
__global__ __launch_bounds__(256)
void qkv_mfma(const float* __restrict__ q_in, const float* __restrict__ k_in,
              const float* __restrict__ v_in,
              const float* __restrict__ Wq, const float* __restrict__ bq,
              const float* __restrict__ Wk, const float* __restrict__ bk,
              const float* __restrict__ Wv, const float* __restrict__ bv,
              unsigned short* __restrict__ Qo, unsigned short* __restrict__ Ko,
              unsigned short* __restrict__ Vo)
{
    const float *A, *W, *B; unsigned short* C;
    if (blockIdx.z == 0)      { A = q_in; W = Wq; B = bq; C = Qo; }
    else if (blockIdx.z == 1) { A = k_in; W = Wk; B = bk; C = Ko; }
    else                      { A = v_in; W = Wv; B = bv; C = Vo; }

    __shared__ __align__(16) short Alds[128*32];
    __shared__ __align__(16) short Blds[128*32];
    const int tid  = threadIdx.x;
    const int lane = tid & 63;
    const int wave = tid >> 6;
    const int lrow = lane & 15;
    const int lq   = lane >> 4;
    const int m0 = blockIdx.x * 128;
    const int n0 = blockIdx.y * 128;
    const int mw = (wave >> 1) * 64;
    const int nw = (wave & 1) * 64;
    const int K  = DMODEL;

    floatx4 zero = {0.f, 0.f, 0.f, 0.f};
    floatx4 acc[4][4];
    #pragma unroll
    for (int i = 0; i < 4; ++i)
        #pragma unroll
        for (int j = 0; j < 4; ++j) acc[i][j] = zero;

    for (int k0 = 0; k0 < K; k0 += 32) {
        #pragma unroll
        for (int rep = 0; rep < 2; ++rep) {
            int chunk = tid + rep * 256;
            int row = chunk >> 2;
            int col = (chunk & 3) << 3;
            *(uint4*)&Alds[row*32 + col] = cvt8(&A[(m0 + row) * K + k0 + col]);
            *(uint4*)&Blds[row*32 + col] = cvt8(&W[(n0 + row) * K + k0 + col]);
        }
        __syncthreads();
        short8 af[4], bfg[4];
        #pragma unroll
        for (int mi = 0; mi < 4; ++mi)
            af[mi] = *(const short8*)&Alds[(mw + mi*16 + lrow)*32 + lq*8];
        #pragma unroll
        for (int ni = 0; ni < 4; ++ni)
            bfg[ni] = *(const short8*)&Blds[(nw + ni*16 + lrow)*32 + lq*8];
        #pragma unroll
        for (int mi = 0; mi < 4; ++mi)
            #pragma unroll
            for (int ni = 0; ni < 4; ++ni)
                acc[mi][ni] = __builtin_amdgcn_mfma_f32_16x16x32_bf16(af[mi], bfg[ni], acc[mi][ni], 0, 0, 0);
        __syncthreads();
    }

    #pragma unroll
    for (int mi = 0; mi < 4; ++mi) {
        #pragma unroll
        for (int ni = 0; ni < 4; ++ni) {
            int n = n0 + nw + ni*16 + lrow;
            float bv_ = B[n];
            #pragma unroll
            for (int r = 0; r < 4; ++r) {
                int m = m0 + mw + mi*16 + lq*4 + r;
                C[m * DMODEL + n] = f2bf(acc[mi][ni][r] + bv_);
            }
        }
    }
}

__global__ __launch_bounds__(256)
void oproj_mfma(const unsigned short* __restrict__ Cx,
                const float* __restrict__ Wo, const float* __restrict__ bo,
                float* __restrict__ O32)
{
    __shared__ __align__(16) short Alds[128*32];
    __shared__ __align__(16) short Blds[128*32];
    const int tid  = threadIdx.x;
    const int lane = tid & 63;
    const int wave = tid >> 6;
    const int lrow = lane & 15;
    const int lq   = lane >> 4;
    const int m0 = blockIdx.x * 128;
    const int n0 = blockIdx.y * 128;
    const int mw = (wave >> 1) * 64;
    const int nw = (wave & 1) * 64;
    const int K  = DMODEL;

    floatx4 zero = {0.f, 0.f, 0.f, 0.f};
    floatx4 acc[4][4];
    #pragma unroll
    for (int i = 0; i < 4; ++i)
        #pragma unroll
        for (int j = 0; j < 4; ++j) acc[i][j] = zero;

    for (int k0 = 0; k0 < K; k0 += 32) {
        #pragma unroll
        for (int rep = 0; rep < 2; ++rep) {
            int chunk = tid + rep * 256;
            int row = chunk >> 2;
            int col = (chunk & 3) << 3;
            *(uint4*)&Alds[row*32 + col] = *(const uint4*)&Cx[(m0 + row) * K + k0 + col];
            *(uint4*)&Blds[row*32 + col] = cvt8(&Wo[(n0 + row) * K + k0 + col]);
        }
        __syncthreads();
        short8 af[4], bfg[4];
        #pragma unroll
        for (int mi = 0; mi < 4; ++mi)
            af[mi] = *(const short8*)&Alds[(mw + mi*16 + lrow)*32 + lq*8];
        #pragma unroll
        for (int ni = 0; ni < 4; ++ni)
            bfg[ni] = *(const short8*)&Blds[(nw + ni*16 + lrow)*32 + lq*8];
        #pragma unroll
        for (int mi = 0; mi < 4; ++mi)
            #pragma unroll
            for (int ni = 0; ni < 4; ++ni)
                acc[mi][ni] = __builtin_amdgcn_mfma_f32_16x16x32_bf16(af[mi], bfg[ni], acc[mi][ni], 0, 0, 0);
        __syncthreads();
    }

    #pragma unroll
    for (int mi = 0; mi < 4; ++mi) {
        #pragma unroll
        for (int ni = 0; ni < 4; ++ni) {
            int n = n0 + nw + ni*16 + lrow;
            float bv_ = bo[n];
            #pragma unroll
            for (int r = 0; r < 4; ++r) {
                int m = m0 + mw + mi*16 + lq*4 + r;
                O32[m * DMODEL + n] = acc[mi][ni][r] + bv_;
            }
        }
    }
}

// ---------------------------------------------------------------
// MFMA flash attention v5 (exp2-domain, VALU-minimized softmax):
//  - Q pre-scaled by log2(e) (in Wq/bq) -> p = exp2(s) native, no mul
//  - sacc initialized to -m_i: the max-subtract is folded into the
//    MFMA accumulator; deferred path has NO per-score subtract
//  - v_max3_f32 tree for row max (8 ops vs 15)
//  - m_i starts at 0 (not -inf): first tile triggers the rescale
//    branch naturally; deferred p bounded by 2^8
//  - double-buffered K/V staging, cvt_pk packing, setprio, Ps swizzle
// NOTE: reference applies NO 1/sqrt(dh) scaling.
// ---------------------------------------------------------------
__global__ __launch_bounds__(256)
void attn_mfma5(const unsigned short* __restrict__ Q,
                const unsigned short* __restrict__ Kg,
                const unsigned short* __restrict__ VT,
                unsigned short* __restrict__ Ctx)
{
    // [0,4096) Ks0 | [4096,8192) Vt0 | [8192,12288) Ks1 | [12288,16384) Vt1
    // [16384,20480) Ps (wave w at +w*1024)     (shorts; 40960 bytes total)
    __shared__ __align__(16) short SMEM[20480];

    const int tid  = threadIdx.x;
    const int lane = tid & 63;
    const int wave = tid >> 6;
    const int lrow = lane & 15;
    const int lq   = lane >> 4;

    const int q0 = blockIdx.x * 64;
    const int bh = blockIdx.y;
    const int off = (bh >> 4) * DMODEL + (bh & 15) * DH;
    const unsigned short* VTb = VT + bh * (DH * SEQ);
    short* const psw = &SMEM[16384 + wave * 1024];

    auto stageKV = [&](int kt, int b) {
        const int kbase = kt * 64;
        short* ksb = &SMEM[b * 8192];
        short* vtb = &SMEM[b * 8192 + 4096];
        #pragma unroll
        for (int rep = 0; rep < 2; ++rep) {
            int c = rep*256 + tid;
            int r = c >> 3, cc = c & 7;
            int sw = ((cc ^ (r & 7)) << 3);
            __builtin_amdgcn_global_load_lds(
                (const AS_GLOBAL unsigned int*)&Kg[(kbase + r) * RS + off + sw],
                (AS_LDS unsigned int*)&ksb[(rep*256 + wave*64) * 8], 16, 0, 0);
            __builtin_amdgcn_global_load_lds(
                (const AS_GLOBAL unsigned int*)&VTb[r * SEQ + kbase + sw],
                (AS_LDS unsigned int*)&vtb[(rep*256 + wave*64) * 8], 16, 0, 0);
        }
    };

    stageKV(0, 0);

    const int qrow = q0 + wave*16 + lrow;
    short8 qf[2];
    qf[0] = *(const short8*)&Q[qrow * RS + off + lq*8];
    qf[1] = *(const short8*)&Q[qrow * RS + off + 32 + lq*8];

    floatx4 zero = {0.f, 0.f, 0.f, 0.f};
    float m_i = 0.f, l_i = 0.f;      // log2 domain; m starts at 0
    floatx4 oacc[4];
    #pragma unroll
    for (int ni = 0; ni < 4; ++ni) oacc[ni] = zero;

    __syncthreads();   // KV0 landed, Q frags in regs

    for (int kt = 0; kt < SEQ/64; ++kt) {
        const int cur = kt & 1;
        if (kt + 1 < SEQ/64) stageKV(kt + 1, cur ^ 1);   // prefetch in flight
        const short* ksb = &SMEM[cur * 8192];
        const short* vtb = &SMEM[cur * 8192 + 4096];

        // ---- S^T - m_i = K Q^T + (-m_i) : acc pre-biased ----
        floatx4 sacc[4];
        const float negm = -m_i;
        floatx4 minit = {negm, negm, negm, negm};
        #pragma unroll
        for (int ni = 0; ni < 4; ++ni) sacc[ni] = minit;
        __builtin_amdgcn_s_setprio(1);
        #pragma unroll
        for (int ni = 0; ni < 4; ++ni) {
            #pragma unroll
            for (int kk = 0; kk < 2; ++kk) {
                int key = ni*16 + lrow;
                int cc  = kk*4 + lq;
                short8 kf = *(const short8*)&ksb[key*64 + ((cc ^ (key & 7)) << 3)];
                sacc[ni] = __builtin_amdgcn_mfma_f32_16x16x32_bf16(kf, qf[kk], sacc[ni], 0, 0, 0);
            }
        }
        __builtin_amdgcn_s_setprio(0);

        // ---- row max (relative to m_i) via max3 tree ----
        float a0 = max3f(sacc[0][0], sacc[0][1], sacc[0][2]);
        float a1 = max3f(sacc[0][3], sacc[1][0], sacc[1][1]);
        float a2 = max3f(sacc[1][2], sacc[1][3], sacc[2][0]);
        float a3 = max3f(sacc[2][1], sacc[2][2], sacc[2][3]);
        float a4 = max3f(sacc[3][0], sacc[3][1], sacc[3][2]);
        float b0 = max3f(a0, a1, a2);
        float b1 = max3f(a3, a4, sacc[3][3]);
        float mx = fmaxf(b0, b1);
        mx = fmaxf(mx, __shfl_xor(mx, 16));
        mx = fmaxf(mx, __shfl_xor(mx, 32));

        float p[4][4];
        if (__all(mx <= 8.f)) {
            // deferred: p = exp2(sacc), no subtract at all
            #pragma unroll
            for (int ni = 0; ni < 4; ++ni)
                #pragma unroll
                for (int r = 0; r < 4; ++r)
                    p[ni][r] = fast_exp2(sacc[ni][r]);
        } else {
            float shift = fmaxf(mx, 0.f);        // never lower m
            float alpha = fast_exp2(-shift);
            l_i *= alpha;
            #pragma unroll
            for (int ni = 0; ni < 4; ++ni)
                #pragma unroll
                for (int r = 0; r < 4; ++r) oacc[ni][r] *= alpha;
            m_i += shift;
            #pragma unroll
            for (int ni = 0; ni < 4; ++ni)
                #pragma unroll
                for (int r = 0; r < 4; ++r)
                    p[ni][r] = fast_exp2(sacc[ni][r] - shift);
        }

        // pairwise psum tree
        float s00 = (p[0][0] + p[0][1]) + (p[0][2] + p[0][3]);
        float s01 = (p[1][0] + p[1][1]) + (p[1][2] + p[1][3]);
        float s10 = (p[2][0] + p[2][1]) + (p[2][2] + p[2][3]);
        float s11 = (p[3][0] + p[3][1]) + (p[3][2] + p[3][3]);
        float psum = (s00 + s01) + (s10 + s11);
        psum += __shfl_xor(psum, 16);
        psum += __shfl_xor(psum, 32);
        l_i += psum;

        // ---- P: PsT[q=lrow][key], 16B-unit XOR swizzle, cvt_pk packing ----
        #pragma unroll
        for (int ni = 0; ni < 4; ++ni) {
            uint2 pk;
            pk.x = cvt_pk_bf16(p[ni][0], p[ni][1]);
            pk.y = cvt_pk_bf16(p[ni][2], p[ni][3]);
            int t  = ni*2 + (lq >> 1);
            int tp = t ^ (lrow & 7);
            *(uint2*)&psw[lrow*64 + tp*8 + (lq & 1)*4] = pk;
        }
        __builtin_amdgcn_wave_barrier();

        short8 pf[2];
        #pragma unroll
        for (int kk = 0; kk < 2; ++kk) {
            int t  = kk*4 + lq;
            int tp = t ^ (lrow & 7);
            pf[kk] = *(const short8*)&psw[lrow*64 + tp*8];
        }

        // ---- O^T += Vt P^T : D[m=d][n=q] ----
        __builtin_amdgcn_s_setprio(1);
        #pragma unroll
        for (int ni = 0; ni < 4; ++ni) {
            #pragma unroll
            for (int kk = 0; kk < 2; ++kk) {
                int d  = ni*16 + lrow;
                int cc = kk*4 + lq;
                short8 vf = *(const short8*)&vtb[d*64 + ((cc ^ (d & 7)) << 3)];
                oacc[ni] = __builtin_amdgcn_mfma_f32_16x16x32_bf16(vf, pf[kk], oacc[ni], 0, 0, 0);
            }
        }
        __builtin_amdgcn_s_setprio(0);

        __syncthreads();   // drains prefetch + buf swap
    }

    const float inv = 1.f / l_i;
    #pragma unroll
    for (int ni = 0; ni < 4; ++ni) {
        uint2 ok;
        ok.x = cvt_pk_bf16(oacc[ni][0] * inv, oacc[ni][1] * inv);
        ok.y = cvt_pk_bf16(oacc[ni][2] * inv, oacc[ni][3] * inv);
        *(uint2*)&Ctx[qrow * RS + off + ni*16 + lq*4] = ok;
    }
}

// ---------------------------------------------------------------
// MFMA flash attention v2 (fallback path: V in normal layout,
// natural-log domain, unscaled weights).
// ---------------------------------------------------------------
__global__ __launch_bounds__(256)
void attn_mfma2(const unsigned short* __restrict__ Q,
                const unsigned short* __restrict__ Kg,
                const unsigned short* __restrict__ V,
                unsigned short* __restrict__ Ctx)
{
    __shared__ __align__(16) short Qs[64*72];
    __shared__ __align__(16) short Ks[64*72];
    __shared__ __align__(16) short Vt[64*72];
    __shared__ __align__(16) short Ps[4][16*72];

    const int tid  = threadIdx.x;
    const int lane = tid & 63;
    const int wave = tid >> 6;
    const int lrow = lane & 15;
    const int lq   = lane >> 4;

    const int q0 = blockIdx.x * 64;
    const int bh = blockIdx.y;
    const int off = (bh >> 4) * DMODEL + (bh & 15) * DH;

    #pragma unroll
    for (int rep = 0; rep < 2; ++rep) {
        int chunk = tid + rep * 256;
        int r = chunk >> 3;
        int c = (chunk & 7) << 3;
        *(uint4*)&Qs[r*72 + c] = *(const uint4*)&Q[(q0 + r) * RS + off + c];
    }
    __syncthreads();

    short8 qf[2];
    #pragma unroll
    for (int ks = 0; ks < 2; ++ks)
        qf[ks] = *(const short8*)&Qs[(wave*16 + lrow)*72 + ks*32 + lq*8];

    floatx4 zero = {0.f, 0.f, 0.f, 0.f};
    float m_i = -1e30f, l_i = 0.f;
    floatx4 oacc[4];
    #pragma unroll
    for (int ni = 0; ni < 4; ++ni) oacc[ni] = zero;

    for (int kt = 0; kt < SEQ/64; ++kt) {
        __syncthreads();
        const int kbase = kt * 64;
        #pragma unroll
        for (int rep = 0; rep < 2; ++rep) {
            int chunk = tid + rep * 256;
            int r = chunk >> 3;
            int c = (chunk & 7) << 3;
            *(uint4*)&Ks[r*72 + c] = *(const uint4*)&Kg[(kbase + r) * RS + off + c];
            uint4 vv = *(const uint4*)&V[(kbase + r) * RS + off + c];
            union { uint4 u; short s[8]; } uv; uv.u = vv;
            int swz = (chunk & 7) << 3;
            #pragma unroll
            for (int j = 0; j < 8; ++j)
                Vt[(c + j)*72 + (r ^ swz)] = uv.s[j];
        }
        __syncthreads();

        floatx4 sacc[4];
        #pragma unroll
        for (int ni = 0; ni < 4; ++ni) sacc[ni] = zero;
        #pragma unroll
        for (int ni = 0; ni < 4; ++ni) {
            #pragma unroll
            for (int ks = 0; ks < 2; ++ks) {
                short8 kf = *(const short8*)&Ks[(ni*16 + lrow)*72 + ks*32 + lq*8];
                sacc[ni] = __builtin_amdgcn_mfma_f32_16x16x32_bf16(kf, qf[ks], sacc[ni], 0, 0, 0);
            }
        }

        float mx = sacc[0][0];
        #pragma unroll
        for (int ni = 0; ni < 4; ++ni)
            #pragma unroll
            for (int r = 0; r < 4; ++r) mx = fmaxf(mx, sacc[ni][r]);
        mx = fmaxf(mx, __shfl_xor(mx, 16));
        mx = fmaxf(mx, __shfl_xor(mx, 32));
        float mnew = fmaxf(m_i, mx);
        float alpha = __expf(m_i - mnew);
        float p[4][4];
        float psum = 0.f;
        #pragma unroll
        for (int ni = 0; ni < 4; ++ni)
            #pragma unroll
            for (int r = 0; r < 4; ++r) {
                p[ni][r] = __expf(sacc[ni][r] - mnew);
                psum += p[ni][r];
            }
        psum += __shfl_xor(psum, 16);
        psum += __shfl_xor(psum, 32);
        l_i = l_i * alpha + psum;
        m_i = mnew;
        #pragma unroll
        for (int ni = 0; ni < 4; ++ni)
            #pragma unroll
            for (int r = 0; r < 4; ++r) oacc[ni][r] *= alpha;

        #pragma unroll
        for (int ni = 0; ni < 4; ++ni) {
            uint2 pk;
            pk.x = (unsigned)f2bf(p[ni][0]) | ((unsigned)f2bf(p[ni][1]) << 16);
            pk.y = (unsigned)f2bf(p[ni][2]) | ((unsigned)f2bf(p[ni][3]) << 16);
            *(uint2*)&Ps[wave][lrow*72 + ni*16 + lq*4] = pk;
        }
        __builtin_amdgcn_wave_barrier();

        short8 pf[2];
        #pragma unroll
        for (int ks = 0; ks < 2; ++ks)
            pf[ks] = *(const short8*)&Ps[wave][lrow*72 + ks*32 + lq*8];
        #pragma unroll
        for (int ni = 0; ni < 4; ++ni) {
            #pragma unroll
            for (int ks = 0; ks < 2; ++ks) {
                int d  = ni*16 + lrow;
                int kk = ks*32 + lq*8;
                int swz = ((d >> 3) & 7) << 3;
                short8 vf = *(const short8*)&Vt[d*72 + (kk ^ swz)];
                oacc[ni] = __builtin_amdgcn_mfma_f32_16x16x32_bf16(vf, pf[ks], oacc[ni], 0, 0, 0);
            }
        }
    }

    const float inv = 1.f / l_i;
    const int q = q0 + wave*16 + lrow;
    #pragma unroll
    for (int ni = 0; ni < 4; ++ni) {
        uint2 ok;
        ok.x = (unsigned)f2bf(oacc[ni][0] * inv) | ((unsigned)f2bf(oacc[ni][1] * inv) << 16);
        ok.y = (unsigned)f2bf(oacc[ni][2] * inv) | ((unsigned)f2bf(oacc[ni][3] * inv) << 16);
        *(uint2*)&Ctx[q * RS + off + ni*16 + lq*4] = ok;
    }
}

// ---------------------------------------------------------------
// LayerNorm(out + residual): fp32 in, fp32 out. Wave-shuffle reduce.
// ---------------------------------------------------------------
__global__ __launch_bounds__(256)
void ln2_kernel(const float* __restrict__ O,
                const float* __restrict__ resid,
                const float* __restrict__ w,
                const float* __restrict__ bb,
                float* __restrict__ out)
{
    __shared__ float r1s[4];
    __shared__ float r2s[4];
    const int row = blockIdx.x;
    const int tid = threadIdx.x;
    const int c4 = tid * 4;

    float4 o4 = *(const float4*)&O[row * DMODEL + c4];
    float4 q4 = *(const float4*)&resid[row * DMODEL + c4];
    float x0 = o4.x + q4.x;
    float x1 = o4.y + q4.y;
    float x2 = o4.z + q4.z;
    float x3 = o4.w + q4.w;

    float s1 = x0 + x1 + x2 + x3;
    float s2 = x0*x0 + x1*x1 + x2*x2 + x3*x3;
    #pragma unroll
    for (int o = 32; o > 0; o >>= 1) {
        s1 += __shfl_xor(s1, o);
        s2 += __shfl_xor(s2, o);
    }
    if ((tid & 63) == 0) { r1s[tid >> 6] = s1; r2s[tid >> 6] = s2; }
    __syncthreads();
    float t1 = r1s[0] + r1s[1] + r1s[2] + r1s[3];
    float t2 = r2s[0] + r2s[1] + r2s[2] + r2s[3];

    const float mean = t1 * (1.f / DMODEL);
    float var = t2 * (1.f / DMODEL) - mean * mean;
    var = fmaxf(var, 0.f);
    const float rstd = rsqrtf(var + LN_EPS);

    float4 w4 = *(const float4*)&w[c4];
    float4 b4 = *(const float4*)&bb[c4];
    float4 y;
    y.x = w4.x * ((x0 - mean) * rstd) + b4.x;
    y.y = w4.y * ((x1 - mean) * rstd) + b4.y;
    y.z = w4.z * ((x2 - mean) * rstd) + b4.z;
    y.w = w4.w * ((x3 - mean) * rstd) + b4.w;
    *(float4*)&out[row * DMODEL + c4] = y;
}

// ---------------------------------------------------------------
extern "C" void kernel_launch(void* const* d_in, const int* in_sizes, int n_in,
                              void* d_out, int out_size, void* d_ws, size_t ws_size,
                              hipStream_t stream) {
    const float* q_in = (const float*)d_in[0];
    const float* k_in = (const float*)d_in[1];
    const float* v_in = (const float*)d_in[2];
    const float* Wq = (const float*)d_in[3];  const float* bq = (const float*)d_in[4];
    const float* Wk = (const float*)d_in[5];  const float* bk = (const float*)d_in[6];
    const float* Wv = (const float*)d_in[7];  const float* bv = (const float*)d_in[8];
    const float* Wo = (const float*)d_in[9];  const float* bo = (const float*)d_in[10];
    const float* lnw = (const float*)d_in[11]; const float* lnb = (const float*)d_in[12];

    char* wsb = (char*)d_ws;
    unsigned short* QCtx = (unsigned short*)d_out;
    float*          outF = (float*)d_out;
    dim3 blk(256);

    if (ws_size >= (48u << 20)) {
        // ws: [0,24) qb,kb,vb | [24,32) W's | [32,40) Kb | [40,48) Vb
        // VT (8MB) overlays qb [0,8) (dead after qkv);
        // O32 (16MB) overlays [0,16) (VT dead after attn).
        unsigned short* qb  = (unsigned short*)(wsb);
        unsigned short* kb  = (unsigned short*)(wsb + (8u  << 20));
        unsigned short* vb  = (unsigned short*)(wsb + (16u << 20));
        unsigned short* Wqb = (unsigned short*)(wsb + (24u << 20));
        unsigned short* Wkb = (unsigned short*)(wsb + (26u << 20));
        unsigned short* Wvb = (unsigned short*)(wsb + (28u << 20));
        unsigned short* Wob = (unsigned short*)(wsb + (30u << 20));
        unsigned short* Kb  = (unsigned short*)(wsb + (32u << 20));
        unsigned short* Vb  = (unsigned short*)(wsb + (40u << 20));
        unsigned short* VT  = (unsigned short*)(wsb);
        float*          O32 = (float*)(wsb);

        cvt_kernel<<<dim3(512, 1, 7), blk, 0, stream>>>(
            q_in, k_in, v_in, Wq, Wk, Wv, Wo,
            qb, kb, vb, Wqb, Wkb, Wvb, Wob);
        qkv_bf16<<<dim3(MROWS/128, DMODEL/128, 3), blk, 0, stream>>>(
            qb, kb, vb, Wqb, bq, Wkb, bk, Wvb, bv, QCtx, Kb, Vb);
        vt_kernel<<<dim3(SEQ/64, BATCH*NHEAD), blk, 0, stream>>>(Vb, VT);
        attn_mfma5<<<dim3(SEQ/64, BATCH*NHEAD), blk, 0, stream>>>(QCtx, Kb, VT, QCtx);
        oproj_bf16<<<dim3(MROWS/128, DMODEL/128), blk, 0, stream>>>(QCtx, Wob, bo, O32);
        ln2_kernel<<<dim3(MROWS), blk, 0, stream>>>(O32, q_in, lnw, lnb, outF);
    } else if (ws_size >= (16u << 20)) {
        unsigned short* Kb  = (unsigned short*)(wsb);
        unsigned short* Vb  = (unsigned short*)(wsb + (8u << 20));
        float*          O32 = (float*)(wsb);
        qkv_mfma<<<dim3(MROWS/128, DMODEL/128, 3), blk, 0, stream>>>(
            q_in, k_in, v_in, Wq, bq, Wk, bk, Wv, bv, QCtx, Kb, Vb);
        attn_mfma2<<<dim3(SEQ/64, BATCH*NHEAD), blk, 0, stream>>>(QCtx, Kb, Vb, QCtx);
        oproj_mfma<<<dim3(MROWS/128, DMODEL/128), blk, 0, stream>>>(QCtx, Wo, bo, O32);
        ln2_kernel<<<dim3(MROWS), blk, 0, stream>>>(O32, q_in, lnw, lnb, outF);
    } else {
        beacon_kernel<<<1, 64, 0, stream>>>((float*)d_out, 300.0f);
    }
}

// Round 4
// 250.159 us; speedup vs baseline: 1.0356x; 1.0356x over previous
//
#include <hip/hip_runtime.h>

#define SEQ    2048
#define BATCH  2
#define DMODEL 1024
#define NHEAD  16
#define DH     64
#define MROWS  (SEQ*BATCH)        // 4096
#define RS     (BATCH*DMODEL)     // 2048
#define LN_EPS 1e-12f
#define LOG2E  1.4426950408889634f

typedef __attribute__((ext_vector_type(8))) short short8;
typedef __attribute__((ext_vector_type(4))) float floatx4;

#define AS_GLOBAL __attribute__((address_space(1)))
#define AS_LDS    __attribute__((address_space(3)))

// ---- bf16 bit helpers (intermediates only; in/out are fp32) ----
__device__ __forceinline__ float bf2f(unsigned short s) {
    union { unsigned u; float f; } a; a.u = ((unsigned)s) << 16; return a.f;
}
__device__ __forceinline__ unsigned short f2bf(float x) {
    union { float f; unsigned u; } a; a.f = x;
    unsigned r = a.u + 0x7fffu + ((a.u >> 16) & 1u);
    return (unsigned short)(r >> 16);
}
// HW packed conversion: lo = cvt(a), hi = cvt(b). One instr for two bf16.
__device__ __forceinline__ unsigned cvt_pk_bf16(float a, float b) {
    unsigned r;
    asm("v_cvt_pk_bf16_f32 %0, %1, %2" : "=v"(r) : "v"(a), "v"(b));
    return r;
}
// 3-input max, single VALU op (VOP3).
__device__ __forceinline__ float max3f(float a, float b, float c) {
    float r;
    asm("v_max3_f32 %0, %1, %2, %3" : "=v"(r) : "v"(a), "v"(b), "v"(c));
    return r;
}
__device__ __forceinline__ float fast_exp2(float x) {
#if __has_builtin(__builtin_amdgcn_exp2f)
    return __builtin_amdgcn_exp2f(x);
#else
    return exp2f(x);
#endif
}
__device__ __forceinline__ uint4 cvt8(const float* __restrict__ p) {
    float4 x0 = *(const float4*)(p);
    float4 x1 = *(const float4*)(p + 4);
    union { uint4 u; unsigned short s[8]; } r;
    r.s[0] = f2bf(x0.x); r.s[1] = f2bf(x0.y);
    r.s[2] = f2bf(x0.z); r.s[3] = f2bf(x0.w);
    r.s[4] = f2bf(x1.x); r.s[5] = f2bf(x1.y);
    r.s[6] = f2bf(x1.z); r.s[7] = f2bf(x1.w);
    return r.u;
}
__device__ __forceinline__ uint4 cvt8s(const float* __restrict__ p, float sc) {
    float4 x0 = *(const float4*)(p);
    float4 x1 = *(const float4*)(p + 4);
    union { uint4 u; unsigned short s[8]; } r;
    r.s[0] = f2bf(x0.x*sc); r.s[1] = f2bf(x0.y*sc);
    r.s[2] = f2bf(x0.z*sc); r.s[3] = f2bf(x0.w*sc);
    r.s[4] = f2bf(x1.x*sc); r.s[5] = f2bf(x1.y*sc);
    r.s[6] = f2bf(x1.z*sc); r.s[7] = f2bf(x1.w*sc);
    return r.u;
}

__global__ void beacon_kernel(float* out, float val) {
    if (threadIdx.x == 0) out[0] = val;
}

// ---------------------------------------------------------------
// One-shot fp32 -> bf16 conversion of inputs + weights.
// Wq (z==3) is pre-scaled by log2(e) so attention softmax can use
// native exp2 without a per-score multiply.
// ---------------------------------------------------------------
__global__ __launch_bounds__(256)
void cvt_kernel(const float* __restrict__ s0, const float* __restrict__ s1,
                const float* __restrict__ s2, const float* __restrict__ s3,
                const float* __restrict__ s4, const float* __restrict__ s5,
                const float* __restrict__ s6,
                unsigned short* __restrict__ d0, unsigned short* __restrict__ d1,
                unsigned short* __restrict__ d2, unsigned short* __restrict__ d3,
                unsigned short* __restrict__ d4, unsigned short* __restrict__ d5,
                unsigned short* __restrict__ d6)
{
    const float* srcs[7] = {s0, s1, s2, s3, s4, s5, s6};
    unsigned short* dsts[7] = {d0, d1, d2, d3, d4, d5, d6};
    const int cnts[7] = {4194304, 4194304, 4194304, 1048576, 1048576, 1048576, 1048576};
    const float scl[7] = {1.f, 1.f, 1.f, LOG2E, 1.f, 1.f, 1.f};
    const int z = blockIdx.z;
    const float* src = srcs[z];
    unsigned short* dst = dsts[z];
    const int count = cnts[z];
    const float sc = scl[z];
    const int stride = gridDim.x * 256 * 8;
    for (int i = (blockIdx.x * 256 + threadIdx.x) * 8; i < count; i += stride)
        *(uint4*)&dst[i] = cvt8s(&src[i], sc);
}

// ---------------------------------------------------------------
// V transpose: Vb [token=(s*2+b)][dmodel] -> VT [bh=32][d=64][s=2048]
// ---------------------------------------------------------------
__global__ __launch_bounds__(256)
void vt_kernel(const unsigned short* __restrict__ Vb,
               unsigned short* __restrict__ VT)
{
    __shared__ __align__(16) short T[64*72];
    const int tid = threadIdx.x;
    const int s0 = blockIdx.x * 64;
    const int bh = blockIdx.y;
    const int b = bh >> 4, h = bh & 15;

    #pragma unroll
    for (int rep = 0; rep < 2; ++rep) {
        int c = tid + rep * 256;
        int s = c >> 3, cc = c & 7;
        *(uint4*)&T[s*72 + cc*8] =
            *(const uint4*)&Vb[((s0 + s) * BATCH + b) * DMODEL + h*64 + cc*8];
    }
    __syncthreads();
    #pragma unroll
    for (int rep = 0; rep < 2; ++rep) {
        int o = tid + rep * 256;
        int d = o >> 3, sc = o & 7;
        union { uint4 u; unsigned short e[8]; } pk;
        #pragma unroll
        for (int j = 0; j < 8; ++j)
            pk.e[j] = (unsigned short)T[(sc*8 + j)*72 + d];
        *(uint4*)&VT[bh*(DH*SEQ) + d*SEQ + s0 + sc*8] = pk.u;
    }
}

// ---------------------------------------------------------------
// bf16 MFMA GEMM, double-buffered async global->LDS staging.
// m0/n0 come from the caller (XCD-swizzled block decode).
// ---------------------------------------------------------------
template<int OUTF32>
__device__ __forceinline__ void gemm_bf16_body(
    const unsigned short* __restrict__ A,
    const unsigned short* __restrict__ W,
    const float* __restrict__ bias, float bscale,
    void* __restrict__ Cout, int m0, int n0)
{
    __shared__ __align__(16) short Alds[2][128*32];
    __shared__ __align__(16) short Blds[2][128*32];

    const int tid  = threadIdx.x;
    const int lane = tid & 63;
    const int wave = tid >> 6;
    const int lrow = lane & 15;
    const int lq   = lane >> 4;
    const int mw = (wave >> 1) * 64;
    const int nw = (wave & 1) * 64;
    const int K  = DMODEL;

    const int chunk0 = tid;
    const int chunk1 = tid + 256;
    const int row0 = chunk0 >> 2, col0 = (chunk0 & 3) << 3;
    const int row1 = chunk1 >> 2, col1 = (chunk1 & 3) << 3;
    const unsigned short* gA0 = &A[(m0 + row0) * K + col0];
    const unsigned short* gA1 = &A[(m0 + row1) * K + col1];
    const unsigned short* gB0 = &W[(n0 + row0) * K + col0];
    const unsigned short* gB1 = &W[(n0 + row1) * K + col1];

    auto stage = [&](int k0, int b) {
        __builtin_amdgcn_global_load_lds((const AS_GLOBAL unsigned int*)(gA0 + k0),
            (AS_LDS unsigned int*)&Alds[b][(wave*64)*8], 16, 0, 0);
        __builtin_amdgcn_global_load_lds((const AS_GLOBAL unsigned int*)(gA1 + k0),
            (AS_LDS unsigned int*)&Alds[b][(256 + wave*64)*8], 16, 0, 0);
        __builtin_amdgcn_global_load_lds((const AS_GLOBAL unsigned int*)(gB0 + k0),
            (AS_LDS unsigned int*)&Blds[b][(wave*64)*8], 16, 0, 0);
        __builtin_amdgcn_global_load_lds((const AS_GLOBAL unsigned int*)(gB1 + k0),
            (AS_LDS unsigned int*)&Blds[b][(256 + wave*64)*8], 16, 0, 0);
    };

    floatx4 zero = {0.f, 0.f, 0.f, 0.f};
    floatx4 acc[4][4];
    #pragma unroll
    for (int i = 0; i < 4; ++i)
        #pragma unroll
        for (int j = 0; j < 4; ++j) acc[i][j] = zero;

    stage(0, 0);
    __syncthreads();

    for (int k0 = 0; k0 < K; k0 += 32) {
        const int cur = (k0 >> 5) & 1;
        if (k0 + 32 < K) stage(k0 + 32, cur ^ 1);   // prefetch in flight
        short8 af[4], bfg[4];
        #pragma unroll
        for (int mi = 0; mi < 4; ++mi)
            af[mi] = *(const short8*)&Alds[cur][(mw + mi*16 + lrow)*32 + lq*8];
        #pragma unroll
        for (int ni = 0; ni < 4; ++ni)
            bfg[ni] = *(const short8*)&Blds[cur][(nw + ni*16 + lrow)*32 + lq*8];
        #pragma unroll
        for (int mi = 0; mi < 4; ++mi)
            #pragma unroll
            for (int ni = 0; ni < 4; ++ni)
                acc[mi][ni] = __builtin_amdgcn_mfma_f32_16x16x32_bf16(af[mi], bfg[ni], acc[mi][ni], 0, 0, 0);
        __syncthreads();   // drains prefetch; protects buf reuse
    }

    #pragma unroll
    for (int mi = 0; mi < 4; ++mi) {
        #pragma unroll
        for (int ni = 0; ni < 4; ++ni) {
            int n = n0 + nw + ni*16 + lrow;
            float bv_ = bias[n] * bscale;
            #pragma unroll
            for (int r = 0; r < 4; ++r) {
                int m = m0 + mw + mi*16 + lq*4 + r;
                float v = acc[mi][ni][r] + bv_;
                if (OUTF32) ((float*)Cout)[m * DMODEL + n] = v;
                else ((unsigned short*)Cout)[m * DMODEL + n] = f2bf(v);
            }
        }
    }
}

// grid = 768 (flat). XCD-swizzled decode: chunk of 96 consecutive swizzled
// ids per XCD covers 8 n-tiles x 12 m-tiles -> per-XCD L2 set A 3MB + B 2MB.
__global__ __launch_bounds__(256)
void qkv_bf16(const unsigned short* __restrict__ qb, const unsigned short* __restrict__ kb,
              const unsigned short* __restrict__ vb,
              const unsigned short* __restrict__ Wqb, const float* __restrict__ bq,
              const unsigned short* __restrict__ Wkb, const float* __restrict__ bk,
              const unsigned short* __restrict__ Wvb, const float* __restrict__ bv,
              unsigned short* __restrict__ Qo, unsigned short* __restrict__ Ko,
              unsigned short* __restrict__ Vo)
{
    const int flat = blockIdx.x;
    const int ns = (flat & 7) * 96 + (flat >> 3);   // bijective (768 % 8 == 0)
    const int z  = ns >> 8;
    const int r  = ns & 255;
    const int n0 = (r & 7) * 128;
    const int m0 = (r >> 3) * 128;

    const unsigned short *A, *W; const float* B; unsigned short* C; float bs;
    if (z == 0)      { A = qb; W = Wqb; B = bq; C = Qo; bs = LOG2E; }
    else if (z == 1) { A = kb; W = Wkb; B = bk; C = Ko; bs = 1.f; }
    else             { A = vb; W = Wvb; B = bv; C = Vo; bs = 1.f; }
    gemm_bf16_body<0>(A, W, B, bs, C, m0, n0);
}

// grid = 256 (flat). Chunk of 32 per XCD: 8 n-tiles x 4 m-tiles.
__global__ __launch_bounds__(256)
void oproj_bf16(const unsigned short* __restrict__ Cx,
                const unsigned short* __restrict__ Wob, const float* __restrict__ bo,
                float* __restrict__ O32)
{
    const int flat = blockIdx.x;
    const int ns = (flat & 7) * 32 + (flat >> 3);
    const int n0 = (ns & 7) * 128;
    const int m0 = (ns >> 3) * 128;
    gemm_bf16_body<1>(Cx, Wob, bo, 1.f, O32, m0, n0);
}

// ---------------- fallback (fused-cvt) GEMMs ----------------
__global__ __launch_bounds__(256)
void qkv_mfma(const float* __restrict__ q_in, const float* __restrict__ k_in,
              const float* __restrict__ v_in,
              const float* __restrict__ Wq, const float* __restrict__ bq,
              const float* __restrict__ Wk, const float* __restrict__ bk,
              const float* __restrict__ Wv, const float* __restrict__ bv,
              unsigned short* __restrict__ Qo, unsigned short* __restrict__ Ko,
              unsigned short* __restrict__ Vo)
{
    const float *A, *W, *B; unsigned short* C;
    if (blockIdx.z == 0)      { A = q_in; W = Wq; B = bq; C = Qo; }
    else if (blockIdx.z == 1) { A = k_in; W = Wk; B = bk; C = Ko; }
    else                      { A = v_in; W = Wv; B = bv; C = Vo; }

    __shared__ __align__(16) short Alds[128*32];
    __shared__ __align__(16) short Blds[128*32];
    const int tid  = threadIdx.x;
    const int lane = tid & 63;
    const int wave = tid >> 6;
    const int lrow = lane & 15;
    const int lq   = lane >> 4;
    const int m0 = blockIdx.x * 128;
    const int n0 = blockIdx.y * 128;
    const int mw = (wave >> 1) * 64;
    const int nw = (wave & 1) * 64;
    const int K  = DMODEL;

    floatx4 zero = {0.f, 0.f, 0.f, 0.f};
    floatx4 acc[4][4];
    #pragma unroll
    for (int i = 0; i < 4; ++i)
        #pragma unroll
        for (int j = 0; j < 4; ++j) acc[i][j] = zero;

    for (int k0 = 0; k0 < K; k0 += 32) {
        #pragma unroll
        for (int rep = 0; rep < 2; ++rep) {
            int chunk = tid + rep * 256;
            int row = chunk >> 2;
            int col = (chunk & 3) << 3;
            *(uint4*)&Alds[row*32 + col] = cvt8(&A[(m0 + row) * K + k0 + col]);
            *(uint4*)&Blds[row*32 + col] = cvt8(&W[(n0 + row) * K + k0 + col]);
        }
        __syncthreads();
        short8 af[4], bfg[4];
        #pragma unroll
        for (int mi = 0; mi < 4; ++mi)
            af[mi] = *(const short8*)&Alds[(mw + mi*16 + lrow)*32 + lq*8];
        #pragma unroll
        for (int ni = 0; ni < 4; ++ni)
            bfg[ni] = *(const short8*)&Blds[(nw + ni*16 + lrow)*32 + lq*8];
        #pragma unroll
        for (int mi = 0; mi < 4; ++mi)
            #pragma unroll
            for (int ni = 0; ni < 4; ++ni)
                acc[mi][ni] = __builtin_amdgcn_mfma_f32_16x16x32_bf16(af[mi], bfg[ni], acc[mi][ni], 0, 0, 0);
        __syncthreads();
    }

    #pragma unroll
    for (int mi = 0; mi < 4; ++mi) {
        #pragma unroll
        for (int ni = 0; ni < 4; ++ni) {
            int n = n0 + nw + ni*16 + lrow;
            float bv_ = B[n];
            #pragma unroll
            for (int r = 0; r < 4; ++r) {
                int m = m0 + mw + mi*16 + lq*4 + r;
                C[m * DMODEL + n] = f2bf(acc[mi][ni][r] + bv_);
            }
        }
    }
}

__global__ __launch_bounds__(256)
void oproj_mfma(const unsigned short* __restrict__ Cx,
                const float* __restrict__ Wo, const float* __restrict__ bo,
                float* __restrict__ O32)
{
    __shared__ __align__(16) short Alds[128*32];
    __shared__ __align__(16) short Blds[128*32];
    const int tid  = threadIdx.x;
    const int lane = tid & 63;
    const int wave = tid >> 6;
    const int lrow = lane & 15;
    const int lq   = lane >> 4;
    const int m0 = blockIdx.x * 128;
    const int n0 = blockIdx.y * 128;
    const int mw = (wave >> 1) * 64;
    const int nw = (wave & 1) * 64;
    const int K  = DMODEL;

    floatx4 zero = {0.f, 0.f, 0.f, 0.f};
    floatx4 acc[4][4];
    #pragma unroll
    for (int i = 0; i < 4; ++i)
        #pragma unroll
        for (int j = 0; j < 4; ++j) acc[i][j] = zero;

    for (int k0 = 0; k0 < K; k0 += 32) {
        #pragma unroll
        for (int rep = 0; rep < 2; ++rep) {
            int chunk = tid + rep * 256;
            int row = chunk >> 2;
            int col = (chunk & 3) << 3;
            *(uint4*)&Alds[row*32 + col] = *(const uint4*)&Cx[(m0 + row) * K + k0 + col];
            *(uint4*)&Blds[row*32 + col] = cvt8(&Wo[(n0 + row) * K + k0 + col]);
        }
        __syncthreads();
        short8 af[4], bfg[4];
        #pragma unroll
        for (int mi = 0; mi < 4; ++mi)
            af[mi] = *(const short8*)&Alds[(mw + mi*16 + lrow)*32 + lq*8];
        #pragma unroll
        for (int ni = 0; ni < 4; ++ni)
            bfg[ni] = *(const short8*)&Blds[(nw + ni*16 + lrow)*32 + lq*8];
        #pragma unroll
        for (int mi = 0; mi < 4; ++mi)
            #pragma unroll
            for (int ni = 0; ni < 4; ++ni)
                acc[mi][ni] = __builtin_amdgcn_mfma_f32_16x16x32_bf16(af[mi], bfg[ni], acc[mi][ni], 0, 0, 0);
        __syncthreads();
    }

    #pragma unroll
    for (int mi = 0; mi < 4; ++mi) {
        #pragma unroll
        for (int ni = 0; ni < 4; ++ni) {
            int n = n0 + nw + ni*16 + lrow;
            float bv_ = bo[n];
            #pragma unroll
            for (int r = 0; r < 4; ++r) {
                int m = m0 + mw + mi*16 + lq*4 + r;
                O32[m * DMODEL + n] = acc[mi][ni][r] + bv_;
            }
        }
    }
}

// ---------------------------------------------------------------
// MFMA flash attention v6 = v4 control flow (the 75.7 us version)
// + dependency-free op cuts + XCD swizzle:
//  - v4 structure: sacc init 0, single-arm defer-rescale, then
//    unconditional p = exp2(sacc - m_i)  (exp2 domain: Q pre-scaled)
//  - v_max3_f32 tree for row max; pairwise psum tree
//  - double-buffered K/V staging, cvt_pk packing, setprio, Ps swizzle
//  - XCD-swizzled (q0, bh): each XCD works 4 bh x 32 q-tiles, so its
//    K/VT working set (2MB) is L2-resident -> faster staging returns
// NOTE: reference applies NO 1/sqrt(dh) scaling.
// ---------------------------------------------------------------
__global__ __launch_bounds__(256)
void attn_mfma6(const unsigned short* __restrict__ Q,
                const unsigned short* __restrict__ Kg,
                const unsigned short* __restrict__ VT,
                unsigned short* __restrict__ Ctx)
{
    // [0,4096) Ks0 | [4096,8192) Vt0 | [8192,12288) Ks1 | [12288,16384) Vt1
    // [16384,20480) Ps (wave w at +w*1024)     (shorts; 40960 bytes total)
    __shared__ __align__(16) short SMEM[20480];

    const int tid  = threadIdx.x;
    const int lane = tid & 63;
    const int wave = tid >> 6;
    const int lrow = lane & 15;
    const int lq   = lane >> 4;

    // XCD-aware bijective swizzle (1024 blocks, 128 per XCD: 4 bh x 32 qx)
    const int flat = blockIdx.x + (blockIdx.y << 5);
    const int ns   = (flat & 7) * 128 + (flat >> 3);
    const int q0 = (ns & 31) * 64;
    const int bh = ns >> 5;

    const int off = (bh >> 4) * DMODEL + (bh & 15) * DH;
    const unsigned short* VTb = VT + bh * (DH * SEQ);
    short* const psw = &SMEM[16384 + wave * 1024];

    auto stageKV = [&](int kt, int b) {
        const int kbase = kt * 64;
        short* ksb = &SMEM[b * 8192];
        short* vtb = &SMEM[b * 8192 + 4096];
        #pragma unroll
        for (int rep = 0; rep < 2; ++rep) {
            int c = rep*256 + tid;
            int r = c >> 3, cc = c & 7;
            int sw = ((cc ^ (r & 7)) << 3);
            __builtin_amdgcn_global_load_lds(
                (const AS_GLOBAL unsigned int*)&Kg[(kbase + r) * RS + off + sw],
                (AS_LDS unsigned int*)&ksb[(rep*256 + wave*64) * 8], 16, 0, 0);
            __builtin_amdgcn_global_load_lds(
                (const AS_GLOBAL unsigned int*)&VTb[r * SEQ + kbase + sw],
                (AS_LDS unsigned int*)&vtb[(rep*256 + wave*64) * 8], 16, 0, 0);
        }
    };

    stageKV(0, 0);

    const int qrow = q0 + wave*16 + lrow;
    short8 qf[2];
    qf[0] = *(const short8*)&Q[qrow * RS + off + lq*8];
    qf[1] = *(const short8*)&Q[qrow * RS + off + 32 + lq*8];

    floatx4 zero = {0.f, 0.f, 0.f, 0.f};
    float m_i = -1e30f, l_i = 0.f;   // log2 domain
    floatx4 oacc[4];
    #pragma unroll
    for (int ni = 0; ni < 4; ++ni) oacc[ni] = zero;

    __syncthreads();   // KV0 landed, Q frags in regs

    for (int kt = 0; kt < SEQ/64; ++kt) {
        const int cur = kt & 1;
        if (kt + 1 < SEQ/64) stageKV(kt + 1, cur ^ 1);   // prefetch in flight
        const short* ksb = &SMEM[cur * 8192];
        const short* vtb = &SMEM[cur * 8192 + 4096];

        // ---- S^T = K Q^T : D[m=key][n=q] ----
        floatx4 sacc[4];
        #pragma unroll
        for (int ni = 0; ni < 4; ++ni) sacc[ni] = zero;
        __builtin_amdgcn_s_setprio(1);
        #pragma unroll
        for (int ni = 0; ni < 4; ++ni) {
            #pragma unroll
            for (int kk = 0; kk < 2; ++kk) {
                int key = ni*16 + lrow;
                int cc  = kk*4 + lq;
                short8 kf = *(const short8*)&ksb[key*64 + ((cc ^ (key & 7)) << 3)];
                sacc[ni] = __builtin_amdgcn_mfma_f32_16x16x32_bf16(kf, qf[kk], sacc[ni], 0, 0, 0);
            }
        }
        __builtin_amdgcn_s_setprio(0);

        // ---- row max via max3 tree ----
        float a0 = max3f(sacc[0][0], sacc[0][1], sacc[0][2]);
        float a1 = max3f(sacc[0][3], sacc[1][0], sacc[1][1]);
        float a2 = max3f(sacc[1][2], sacc[1][3], sacc[2][0]);
        float a3 = max3f(sacc[2][1], sacc[2][2], sacc[2][3]);
        float a4 = max3f(sacc[3][0], sacc[3][1], sacc[3][2]);
        float b0 = max3f(a0, a1, a2);
        float b1 = max3f(a3, a4, sacc[3][3]);
        float mx = fmaxf(b0, b1);
        mx = fmaxf(mx, __shfl_xor(mx, 16));
        mx = fmaxf(mx, __shfl_xor(mx, 32));

        // ---- defer-max rescale (single-arm, v4 structure) ----
        if (!__all(mx <= m_i + 8.f)) {
            float mnew = fmaxf(m_i, mx);
            float alpha = fast_exp2(m_i - mnew);
            l_i *= alpha;
            #pragma unroll
            for (int ni = 0; ni < 4; ++ni)
                #pragma unroll
                for (int r = 0; r < 4; ++r) oacc[ni][r] *= alpha;
            m_i = mnew;
        }
        float p[4][4];
        #pragma unroll
        for (int ni = 0; ni < 4; ++ni)
            #pragma unroll
            for (int r = 0; r < 4; ++r)
                p[ni][r] = fast_exp2(sacc[ni][r] - m_i);   // bounded by 2^8

        // pairwise psum tree
        float s00 = (p[0][0] + p[0][1]) + (p[0][2] + p[0][3]);
        float s01 = (p[1][0] + p[1][1]) + (p[1][2] + p[1][3]);
        float s10 = (p[2][0] + p[2][1]) + (p[2][2] + p[2][3]);
        float s11 = (p[3][0] + p[3][1]) + (p[3][2] + p[3][3]);
        float psum = (s00 + s01) + (s10 + s11);
        psum += __shfl_xor(psum, 16);
        psum += __shfl_xor(psum, 32);
        l_i += psum;

        // ---- P: PsT[q=lrow][key], 16B-unit XOR swizzle, cvt_pk packing ----
        #pragma unroll
        for (int ni = 0; ni < 4; ++ni) {
            uint2 pk;
            pk.x = cvt_pk_bf16(p[ni][0], p[ni][1]);
            pk.y = cvt_pk_bf16(p[ni][2], p[ni][3]);
            int t  = ni*2 + (lq >> 1);
            int tp = t ^ (lrow & 7);
            *(uint2*)&psw[lrow*64 + tp*8 + (lq & 1)*4] = pk;
        }
        __builtin_amdgcn_wave_barrier();

        short8 pf[2];
        #pragma unroll
        for (int kk = 0; kk < 2; ++kk) {
            int t  = kk*4 + lq;
            int tp = t ^ (lrow & 7);
            pf[kk] = *(const short8*)&psw[lrow*64 + tp*8];
        }

        // ---- O^T += Vt P^T : D[m=d][n=q] ----
        __builtin_amdgcn_s_setprio(1);
        #pragma unroll
        for (int ni = 0; ni < 4; ++ni) {
            #pragma unroll
            for (int kk = 0; kk < 2; ++kk) {
                int d  = ni*16 + lrow;
                int cc = kk*4 + lq;
                short8 vf = *(const short8*)&vtb[d*64 + ((cc ^ (d & 7)) << 3)];
                oacc[ni] = __builtin_amdgcn_mfma_f32_16x16x32_bf16(vf, pf[kk], oacc[ni], 0, 0, 0);
            }
        }
        __builtin_amdgcn_s_setprio(0);

        __syncthreads();   // drains prefetch + buf swap
    }

    const float inv = 1.f / l_i;
    #pragma unroll
    for (int ni = 0; ni < 4; ++ni) {
        uint2 ok;
        ok.x = cvt_pk_bf16(oacc[ni][0] * inv, oacc[ni][1] * inv);
        ok.y = cvt_pk_bf16(oacc[ni][2] * inv, oacc[ni][3] * inv);
        *(uint2*)&Ctx[qrow * RS + off + ni*16 + lq*4] = ok;
    }
}

// ---------------------------------------------------------------
// MFMA flash attention v2 (fallback path: V in normal layout,
// natural-log domain, unscaled weights).
// ---------------------------------------------------------------
__global__ __launch_bounds__(256)
void attn_mfma2(const unsigned short* __restrict__ Q,
                const unsigned short* __restrict__ Kg,
                const unsigned short* __restrict__ V,
                unsigned short* __restrict__ Ctx)
{
    __shared__ __align__(16) short Qs[64*72];
    __shared__ __align__(16) short Ks[64*72];
    __shared__ __align__(16) short Vt[64*72];
    __shared__ __align__(16) short Ps[4][16*72];

    const int tid  = threadIdx.x;
    const int lane = tid & 63;
    const int wave = tid >> 6;
    const int lrow = lane & 15;
    const int lq   = lane >> 4;

    const int q0 = blockIdx.x * 64;
    const int bh = blockIdx.y;
    const int off = (bh >> 4) * DMODEL + (bh & 15) * DH;

    #pragma unroll
    for (int rep = 0; rep < 2; ++rep) {
        int chunk = tid + rep * 256;
        int r = chunk >> 3;
        int c = (chunk & 7) << 3;
        *(uint4*)&Qs[r*72 + c] = *(const uint4*)&Q[(q0 + r) * RS + off + c];
    }
    __syncthreads();

    short8 qf[2];
    #pragma unroll
    for (int ks = 0; ks < 2; ++ks)
        qf[ks] = *(const short8*)&Qs[(wave*16 + lrow)*72 + ks*32 + lq*8];

    floatx4 zero = {0.f, 0.f, 0.f, 0.f};
    float m_i = -1e30f, l_i = 0.f;
    floatx4 oacc[4];
    #pragma unroll
    for (int ni = 0; ni < 4; ++ni) oacc[ni] = zero;

    for (int kt = 0; kt < SEQ/64; ++kt) {
        __syncthreads();
        const int kbase = kt * 64;
        #pragma unroll
        for (int rep = 0; rep < 2; ++rep) {
            int chunk = tid + rep * 256;
            int r = chunk >> 3;
            int c = (chunk & 7) << 3;
            *(uint4*)&Ks[r*72 + c] = *(const uint4*)&Kg[(kbase + r) * RS + off + c];
            uint4 vv = *(const uint4*)&V[(kbase + r) * RS + off + c];
            union { uint4 u; short s[8]; } uv; uv.u = vv;
            int swz = (chunk & 7) << 3;
            #pragma unroll
            for (int j = 0; j < 8; ++j)
                Vt[(c + j)*72 + (r ^ swz)] = uv.s[j];
        }
        __syncthreads();

        floatx4 sacc[4];
        #pragma unroll
        for (int ni = 0; ni < 4; ++ni) sacc[ni] = zero;
        #pragma unroll
        for (int ni = 0; ni < 4; ++ni) {
            #pragma unroll
            for (int ks = 0; ks < 2; ++ks) {
                short8 kf = *(const short8*)&Ks[(ni*16 + lrow)*72 + ks*32 + lq*8];
                sacc[ni] = __builtin_amdgcn_mfma_f32_16x16x32_bf16(kf, qf[ks], sacc[ni], 0, 0, 0);
            }
        }

        float mx = sacc[0][0];
        #pragma unroll
        for (int ni = 0; ni < 4; ++ni)
            #pragma unroll
            for (int r = 0; r < 4; ++r) mx = fmaxf(mx, sacc[ni][r]);
        mx = fmaxf(mx, __shfl_xor(mx, 16));
        mx = fmaxf(mx, __shfl_xor(mx, 32));
        float mnew = fmaxf(m_i, mx);
        float alpha = __expf(m_i - mnew);
        float p[4][4];
        float psum = 0.f;
        #pragma unroll
        for (int ni = 0; ni < 4; ++ni)
            #pragma unroll
            for (int r = 0; r < 4; ++r) {
                p[ni][r] = __expf(sacc[ni][r] - mnew);
                psum += p[ni][r];
            }
        psum += __shfl_xor(psum, 16);
        psum += __shfl_xor(psum, 32);
        l_i = l_i * alpha + psum;
        m_i = mnew;
        #pragma unroll
        for (int ni = 0; ni < 4; ++ni)
            #pragma unroll
            for (int r = 0; r < 4; ++r) oacc[ni][r] *= alpha;

        #pragma unroll
        for (int ni = 0; ni < 4; ++ni) {
            uint2 pk;
            pk.x = (unsigned)f2bf(p[ni][0]) | ((unsigned)f2bf(p[ni][1]) << 16);
            pk.y = (unsigned)f2bf(p[ni][2]) | ((unsigned)f2bf(p[ni][3]) << 16);
            *(uint2*)&Ps[wave][lrow*72 + ni*16 + lq*4] = pk;
        }
        __builtin_amdgcn_wave_barrier();

        short8 pf[2];
        #pragma unroll
        for (int ks = 0; ks < 2; ++ks)
            pf[ks] = *(const short8*)&Ps[wave][lrow*72 + ks*32 + lq*8];
        #pragma unroll
        for (int ni = 0; ni < 4; ++ni) {
            #pragma unroll
            for (int ks = 0; ks < 2; ++ks) {
                int d  = ni*16 + lrow;
                int kk = ks*32 + lq*8;
                int swz = ((d >> 3) & 7) << 3;
                short8 vf = *(const short8*)&Vt[d*72 + (kk ^ swz)];
                oacc[ni] = __builtin_amdgcn_mfma_f32_16x16x32_bf16(vf, pf[ks], oacc[ni], 0, 0, 0);
            }
        }
    }

    const float inv = 1.f / l_i;
    const int q = q0 + wave*16 + lrow;
    #pragma unroll
    for (int ni = 0; ni < 4; ++ni) {
        uint2 ok;
        ok.x = (unsigned)f2bf(oacc[ni][0] * inv) | ((unsigned)f2bf(oacc[ni][1] * inv) << 16);
        ok.y = (unsigned)f2bf(oacc[ni][2] * inv) | ((unsigned)f2bf(oacc[ni][3] * inv) << 16);
        *(uint2*)&Ctx[q * RS + off + ni*16 + lq*4] = ok;
    }
}

// ---------------------------------------------------------------
// LayerNorm(out + residual): fp32 in, fp32 out. Wave-shuffle reduce.
// ---------------------------------------------------------------
__global__ __launch_bounds__(256)
void ln2_kernel(const float* __restrict__ O,
                const float* __restrict__ resid,
                const float* __restrict__ w,
                const float* __restrict__ bb,
                float* __restrict__ out)
{
    __shared__ float r1s[4];
    __shared__ float r2s[4];
    const int row = blockIdx.x;
    const int tid = threadIdx.x;
    const int c4 = tid * 4;

    float4 o4 = *(const float4*)&O[row * DMODEL + c4];
    float4 q4 = *(const float4*)&resid[row * DMODEL + c4];
    float x0 = o4.x + q4.x;
    float x1 = o4.y + q4.y;
    float x2 = o4.z + q4.z;
    float x3 = o4.w + q4.w;

    float s1 = x0 + x1 + x2 + x3;
    float s2 = x0*x0 + x1*x1 + x2*x2 + x3*x3;
    #pragma unroll
    for (int o = 32; o > 0; o >>= 1) {
        s1 += __shfl_xor(s1, o);
        s2 += __shfl_xor(s2, o);
    }
    if ((tid & 63) == 0) { r1s[tid >> 6] = s1; r2s[tid >> 6] = s2; }
    __syncthreads();
    float t1 = r1s[0] + r1s[1] + r1s[2] + r1s[3];
    float t2 = r2s[0] + r2s[1] + r2s[2] + r2s[3];

    const float mean = t1 * (1.f / DMODEL);
    float var = t2 * (1.f / DMODEL) - mean * mean;
    var = fmaxf(var, 0.f);
    const float rstd = rsqrtf(var + LN_EPS);

    float4 w4 = *(const float4*)&w[c4];
    float4 b4 = *(const float4*)&bb[c4];
    float4 y;
    y.x = w4.x * ((x0 - mean) * rstd) + b4.x;
    y.y = w4.y * ((x1 - mean) * rstd) + b4.y;
    y.z = w4.z * ((x2 - mean) * rstd) + b4.z;
    y.w = w4.w * ((x3 - mean) * rstd) + b4.w;
    *(float4*)&out[row * DMODEL + c4] = y;
}

// ---------------------------------------------------------------
extern "C" void kernel_launch(void* const* d_in, const int* in_sizes, int n_in,
                              void* d_out, int out_size, void* d_ws, size_t ws_size,
                              hipStream_t stream) {
    const float* q_in = (const float*)d_in[0];
    const float* k_in = (const float*)d_in[1];
    const float* v_in = (const float*)d_in[2];
    const float* Wq = (const float*)d_in[3];  const float* bq = (const float*)d_in[4];
    const float* Wk = (const float*)d_in[5];  const float* bk = (const float*)d_in[6];
    const float* Wv = (const float*)d_in[7];  const float* bv = (const float*)d_in[8];
    const float* Wo = (const float*)d_in[9];  const float* bo = (const float*)d_in[10];
    const float* lnw = (const float*)d_in[11]; const float* lnb = (const float*)d_in[12];

    char* wsb = (char*)d_ws;
    unsigned short* QCtx = (unsigned short*)d_out;
    float*          outF = (float*)d_out;
    dim3 blk(256);

    if (ws_size >= (48u << 20)) {
        // ws: [0,24) qb,kb,vb | [24,32) W's | [32,40) Kb | [40,48) Vb
        // VT (8MB) overlays qb [0,8) (dead after qkv);
        // O32 (16MB) overlays [0,16) (VT dead after attn).
        unsigned short* qb  = (unsigned short*)(wsb);
        unsigned short* kb  = (unsigned short*)(wsb + (8u  << 20));
        unsigned short* vb  = (unsigned short*)(wsb + (16u << 20));
        unsigned short* Wqb = (unsigned short*)(wsb + (24u << 20));
        unsigned short* Wkb = (unsigned short*)(wsb + (26u << 20));
        unsigned short* Wvb = (unsigned short*)(wsb + (28u << 20));
        unsigned short* Wob = (unsigned short*)(wsb + (30u << 20));
        unsigned short* Kb  = (unsigned short*)(wsb + (32u << 20));
        unsigned short* Vb  = (unsigned short*)(wsb + (40u << 20));
        unsigned short* VT  = (unsigned short*)(wsb);
        float*          O32 = (float*)(wsb);

        cvt_kernel<<<dim3(512, 1, 7), blk, 0, stream>>>(
            q_in, k_in, v_in, Wq, Wk, Wv, Wo,
            qb, kb, vb, Wqb, Wkb, Wvb, Wob);
        qkv_bf16<<<dim3(768), blk, 0, stream>>>(
            qb, kb, vb, Wqb, bq, Wkb, bk, Wvb, bv, QCtx, Kb, Vb);
        vt_kernel<<<dim3(SEQ/64, BATCH*NHEAD), blk, 0, stream>>>(Vb, VT);
        attn_mfma6<<<dim3(SEQ/64, BATCH*NHEAD), blk, 0, stream>>>(QCtx, Kb, VT, QCtx);
        oproj_bf16<<<dim3(256), blk, 0, stream>>>(QCtx, Wob, bo, O32);
        ln2_kernel<<<dim3(MROWS), blk, 0, stream>>>(O32, q_in, lnw, lnb, outF);
    } else if (ws_size >= (16u << 20)) {
        unsigned short* Kb  = (unsigned short*)(wsb);
        unsigned short* Vb  = (unsigned short*)(wsb + (8u << 20));
        float*          O32 = (float*)(wsb);
        qkv_mfma<<<dim3(MROWS/128, DMODEL/128, 3), blk, 0, stream>>>(
            q_in, k_in, v_in, Wq, bq, Wk, bk, Wv, bv, QCtx, Kb, Vb);
        attn_mfma2<<<dim3(SEQ/64, BATCH*NHEAD), blk, 0, stream>>>(QCtx, Kb, Vb, QCtx);
        oproj_mfma<<<dim3(MROWS/128, DMODEL/128), blk, 0, stream>>>(QCtx, Wo, bo, O32);
        ln2_kernel<<<dim3(MROWS), blk, 0, stream>>>(O32, q_in, lnw, lnb, outF);
    } else {
        beacon_kernel<<<1, 64, 0, stream>>>((float*)d_out, 300.0f);
    }
}